// Round 1
// baseline (6162.325 us; speedup 1.0000x reference)
//
#include <hip/hip_runtime.h>

#define B_TOT 1024
#define L_T   100
#define DIN   32
#define HID   128
#define DOUT  32
#define BT    16     // batch rows per block (= MFMA M)
#define NBLK  64     // 1024 / 16
#define NTHREADS 512 // 8 waves

typedef _Float16 half8 __attribute__((ext_vector_type(8)));
typedef float    f32x4 __attribute__((ext_vector_type(4)));

// XOR-swizzled index into a [16][128] (or [16][<=128]) f16 LDS tile.
// byte ^= (row&7)<<4  <=>  halfIdx: col ^= (row&7)<<3. Keeps 16B alignment.
#define SWZ(r,c) (((r) << 7) + ((c) ^ (((r) & 7) << 3)))

__device__ __forceinline__ float fast_exp2(float x){
#if __has_builtin(__builtin_amdgcn_exp2f)
  return __builtin_amdgcn_exp2f(x);
#else
  float r; asm("v_exp_f32 %0, %1\n\ts_nop 1" : "=v"(r) : "v"(x)); return r;
#endif
}
__device__ __forceinline__ float fast_rcp(float x){
#if __has_builtin(__builtin_amdgcn_rcpf)
  return __builtin_amdgcn_rcpf(x);
#else
  float r; asm("v_rcp_f32 %0, %1\n\ts_nop 1" : "=v"(r) : "v"(x)); return r;
#endif
}
// tanh(x) = 1 - 2/(e^{2x}+1); exp2/rcp are ~1ulp -> abs err ~1e-7
__device__ __forceinline__ float fast_tanh(float x){
  float e = fast_exp2(x * 2.885390081777926f);  // 2*log2(e)
  return 1.0f - 2.0f * fast_rcp(e + 1.0f);
}

// Reorder a [N][K] f32 row-major weight into fragment-ready f16 tiles:
// dst[ ((tile*(K/32) + k0)*64 + lane)*8 + ki ], lane = (n&15) + 16*((k>>3)&3),
// so a wave's B-fragment load is one coalesced 16B/lane read.
__global__ void reorder_w(const float* __restrict__ src, _Float16* __restrict__ dst,
                          int N, int K){
  int id = blockIdx.x * 256 + threadIdx.x;
  if (id >= N * K) return;
  int n = id / K, k = id - n * K;
  int tile = n >> 4, nl = n & 15;
  int kq = (k >> 3) & 3, k0 = k >> 5, ki = k & 7;
  int lane = nl + (kq << 4);
  int K32 = K >> 5;
  dst[(((tile * K32 + k0) << 6) + lane) * 8 + ki] = (_Float16)src[id];
}

__global__ __launch_bounds__(NTHREADS) void cde_main(
    const float* __restrict__ coeffs, const float* __restrict__ times,
    const float* __restrict__ init_b, const float* __restrict__ fb0,
    const float* __restrict__ fb1,    const float* __restrict__ fb2,
    const float* __restrict__ fbf,    const float* __restrict__ dec_b,
    const _Float16* __restrict__ W,   float* __restrict__ out)
{
  __shared__ _Float16 actZ[BT*HID];  // staged f16 stage-input z (swizzled)
  __shared__ _Float16 actB[BT*HID];
  __shared__ _Float16 actC[BT*HID];
  __shared__ float zf[BT][HID];      // fp32 master z
  __shared__ float dzs[BT][HID];     // vf output dz
  __shared__ float kacc[BT][HID];    // RK4 k-accumulator
  __shared__ float dxs[BT][DIN];     // dX/dt for current interval

  const int tid  = threadIdx.x;
  const int lane = tid & 63;
  const int w    = tid >> 6;   // wave 0..7
  const int cl   = lane & 15;  // tile col / A row
  const int g    = lane >> 4;  // k-group / row-group
  const int b0   = blockIdx.x * BT;

  const _Float16* W0 = W;
  const _Float16* W1 = W + 16384;
  const _Float16* W2 = W + 32768;
  const _Float16* Wf = W + 49152;   // fwf: 4096x128 -> 256 tiles
  const _Float16* Wi = W + 573440;  // init_w: 128x32 -> 8 tiles, K32=1
  const _Float16* Wd = W + 577536;  // dec_w: 32x128 -> 2 tiles

  float dxlo[4], dxhi[4];

  // small dense layer (HID->HID), wave w owns output tile w (cols 16w..16w+15)
  auto dense = [&](const _Float16* in, _Float16* ob, const _Float16* Wt, const float* bias){
    f32x4 acc = {0.f, 0.f, 0.f, 0.f};
#pragma unroll
    for (int kq = 0; kq < 4; ++kq){
      half8 a = *(const half8*)(in + SWZ(cl, kq*32 + 8*g));
      half8 b = *(const half8*)(Wt + ((w*4 + kq)*64 + lane)*8);
      acc = __builtin_amdgcn_mfma_f32_16x16x32_f16(a, b, acc, 0, 0, 0);
    }
    float bn = bias[w*16 + cl];
#pragma unroll
    for (int r = 0; r < 4; ++r)
      ob[SWZ(4*g + r, w*16 + cl)] = (_Float16)fast_tanh(acc[r] + bn);
  };

  // big layer (HID->HID*DIN) fused with tanh and einsum('bhd,bd->bh')
  auto biglayer = [&](const _Float16* in){
    half8 af[4];
#pragma unroll
    for (int kq = 0; kq < 4; ++kq)
      af[kq] = *(const half8*)(in + SWZ(cl, kq*32 + 8*g));
#pragma unroll 2
    for (int hh = 0; hh < 16; ++hh){
      int h  = w*16 + hh;       // this wave's h values: 16w..16w+15
      int tA = 2*h, tB = tA + 1; // d = 0..15 tile, d = 16..31 tile
      f32x4 aA = {0.f,0.f,0.f,0.f}, aB = {0.f,0.f,0.f,0.f};
#pragma unroll
      for (int kq = 0; kq < 4; ++kq){
        half8 bA = *(const half8*)(Wf + ((tA*4 + kq)*64 + lane)*8);
        aA = __builtin_amdgcn_mfma_f32_16x16x32_f16(af[kq], bA, aA, 0, 0, 0);
      }
#pragma unroll
      for (int kq = 0; kq < 4; ++kq){
        half8 bB = *(const half8*)(Wf + ((tB*4 + kq)*64 + lane)*8);
        aB = __builtin_amdgcn_mfma_f32_16x16x32_f16(af[kq], bB, aB, 0, 0, 0);
      }
      float bnA = fbf[tA*16 + cl], bnB = fbf[tB*16 + cl];
      float p[4];
#pragma unroll
      for (int r = 0; r < 4; ++r)
        p[r] = fast_tanh(aA[r] + bnA) * dxlo[r] + fast_tanh(aB[r] + bnB) * dxhi[r];
      // butterfly sum over the 16 cols (d) within each 16-lane group
#pragma unroll
      for (int m = 1; m < 16; m <<= 1){
#pragma unroll
        for (int r = 0; r < 4; ++r) p[r] += __shfl_xor(p[r], m, 64);
      }
      if (cl == 0){
#pragma unroll
        for (int r = 0; r < 4; ++r) dzs[4*g + r][h] = p[r];
      }
    }
  };

  // decoder: out[:, ts, :] = z @ dec_w.T + dec_b, reads actZ (staged z)
  auto decoder = [&](int ts){
    if (w < 2){
      f32x4 acc = {0.f, 0.f, 0.f, 0.f};
#pragma unroll
      for (int kq = 0; kq < 4; ++kq){
        half8 a = *(const half8*)(actZ + SWZ(cl, kq*32 + 8*g));
        half8 b = *(const half8*)(Wd + ((w*4 + kq)*64 + lane)*8);
        acc = __builtin_amdgcn_mfma_f32_16x16x32_f16(a, b, acc, 0, 0, 0);
      }
      float bn = dec_b[w*16 + cl];
#pragma unroll
      for (int r = 0; r < 4; ++r)
        out[(b0 + 4*g + r)*(L_T*DOUT) + ts*DOUT + w*16 + cl] = acc[r] + bn;
    }
  };

  // RK4 combine after stage s; prepares next stage input in actZ
  auto combine = [&](int s, float dt){
#pragma unroll
    for (int j = 0; j < 4; ++j){
      int e = tid + NTHREADS*j;   // 2048 elems
      int r = e >> 7, c = e & 127;
      float kv = dzs[r][c];
      float nin;
      if (s == 0){ kacc[r][c] = kv;            nin = zf[r][c] + 0.5f*dt*kv; }
      else if (s == 1){ kacc[r][c] += 2.0f*kv; nin = zf[r][c] + 0.5f*dt*kv; }
      else if (s == 2){ kacc[r][c] += 2.0f*kv; nin = zf[r][c] + dt*kv; }
      else {
        float zn = zf[r][c] + (dt * (1.0f/6.0f)) * (kacc[r][c] + kv);
        zf[r][c] = zn; nin = zn;
      }
      actZ[SWZ(r, c)] = (_Float16)nin;
    }
  };

  // ---- init: z0 = coeffs[:,0,:] @ init_w.T + init_b ----
  {
    int r = tid >> 5, d = tid & 31;
    actC[SWZ(r, d)] = (_Float16)coeffs[(b0 + r)*(L_T*DIN) + d];
  }
  __syncthreads();
  {
    f32x4 acc = {0.f, 0.f, 0.f, 0.f};
    half8 a = *(const half8*)(actC + SWZ(cl, 8*g));       // K=32 in one MFMA
    half8 b = *(const half8*)(Wi + ((w*64 + lane)*8));    // K32=1
    acc = __builtin_amdgcn_mfma_f32_16x16x32_f16(a, b, acc, 0, 0, 0);
    float bn = init_b[w*16 + cl];
#pragma unroll
    for (int r = 0; r < 4; ++r){
      float v = acc[r] + bn;
      zf[4*g + r][w*16 + cl] = v;
      actZ[SWZ(4*g + r, w*16 + cl)] = (_Float16)v;
    }
  }
  __syncthreads();
  decoder(0);

  // ---- time loop ----
  for (int t = 0; t < L_T - 1; ++t){
    float dt = times[t+1] - times[t];
    {
      int r = tid >> 5, d = tid & 31;
      const float* cp = coeffs + (b0 + r)*(L_T*DIN) + t*DIN + d;
      dxs[r][d] = (cp[DIN] - cp[0]) / dt;
    }
    __syncthreads();
#pragma unroll
    for (int r = 0; r < 4; ++r){
      dxlo[r] = dxs[4*g + r][cl];
      dxhi[r] = dxs[4*g + r][16 + cl];
    }
    for (int s = 0; s < 4; ++s){
      dense(actZ, actB, W0, fb0); __syncthreads();
      dense(actB, actC, W1, fb1); __syncthreads();
      dense(actC, actB, W2, fb2); __syncthreads();
      biglayer(actB);             __syncthreads();
      combine(s, dt);             __syncthreads();
    }
    decoder(t + 1);
  }
}

extern "C" void kernel_launch(void* const* d_in, const int* in_sizes, int n_in,
                              void* d_out, int out_size, void* d_ws, size_t ws_size,
                              hipStream_t stream){
  const float* coeffs = (const float*)d_in[0];
  const float* times  = (const float*)d_in[1];
  const float* init_w = (const float*)d_in[2];
  const float* init_b = (const float*)d_in[3];
  const float* fw0    = (const float*)d_in[4];
  const float* fb0    = (const float*)d_in[5];
  const float* fw1    = (const float*)d_in[6];
  const float* fb1    = (const float*)d_in[7];
  const float* fw2    = (const float*)d_in[8];
  const float* fb2    = (const float*)d_in[9];
  const float* fwf    = (const float*)d_in[10];
  const float* fbf    = (const float*)d_in[11];
  const float* dec_w  = (const float*)d_in[12];
  const float* dec_b  = (const float*)d_in[13];
  _Float16* W = (_Float16*)d_ws;

  hipLaunchKernelGGL(reorder_w, dim3(64),   dim3(256), 0, stream, fw0, W,          128, 128);
  hipLaunchKernelGGL(reorder_w, dim3(64),   dim3(256), 0, stream, fw1, W + 16384,  128, 128);
  hipLaunchKernelGGL(reorder_w, dim3(64),   dim3(256), 0, stream, fw2, W + 32768,  128, 128);
  hipLaunchKernelGGL(reorder_w, dim3(2048), dim3(256), 0, stream, fwf, W + 49152,  4096, 128);
  hipLaunchKernelGGL(reorder_w, dim3(16),   dim3(256), 0, stream, init_w, W + 573440, 128, 32);
  hipLaunchKernelGGL(reorder_w, dim3(16),   dim3(256), 0, stream, dec_w,  W + 577536,  32, 128);

  hipLaunchKernelGGL(cde_main, dim3(NBLK), dim3(NTHREADS), 0, stream,
                     coeffs, times, init_b, fb0, fb1, fb2, fbf, dec_b,
                     W, (float*)d_out);
}